// Round 1
// baseline (550.921 us; speedup 1.0000x reference)
//
#include <hip/hip_runtime.h>
#include <hip/hip_bf16.h>
#include <math.h>

#define N_AGENTS 8192
#define LATENT   128
#define HIDDEN   32
#define MSG      64
#define CONCAT   96      // HIDDEN + MSG
#define THRESH   1.5f

typedef float f32x4 __attribute__((ext_vector_type(4)));

// ---------------- JAX threefry2x32, key = (0, 42) ----------------
__device__ __forceinline__ unsigned rotl32(unsigned x, unsigned r) {
  return (x << r) | (x >> (32u - r));
}
__device__ __forceinline__ void tf_round(unsigned &x0, unsigned &x1, unsigned r) {
  x0 += x1; x1 = rotl32(x1, r); x1 ^= x0;
}
__device__ __forceinline__ uint2 threefry_0_42(unsigned x0, unsigned x1) {
  const unsigned k0 = 0u, k1 = 42u, k2 = 0x1BD11BDAu ^ 0u ^ 42u;
  x0 += k0; x1 += k1;
  tf_round(x0,x1,13); tf_round(x0,x1,15); tf_round(x0,x1,26); tf_round(x0,x1, 6);
  x0 += k1; x1 += k2 + 1u;
  tf_round(x0,x1,17); tf_round(x0,x1,29); tf_round(x0,x1,16); tf_round(x0,x1,24);
  x0 += k2; x1 += k0 + 2u;
  tf_round(x0,x1,13); tf_round(x0,x1,15); tf_round(x0,x1,26); tf_round(x0,x1, 6);
  x0 += k0; x1 += k1 + 3u;
  tf_round(x0,x1,17); tf_round(x0,x1,29); tf_round(x0,x1,16); tf_round(x0,x1,24);
  x0 += k1; x1 += k2 + 4u;
  tf_round(x0,x1,13); tf_round(x0,x1,15); tf_round(x0,x1,26); tf_round(x0,x1, 6);
  x0 += k2; x1 += k0 + 5u;
  return make_uint2(x0, x1);
}

// gumbel for flat index idx of jax.random.uniform(key(42), (8192,64), f32, 1e-10, 1.0)
__device__ __forceinline__ float gumbel_at(unsigned idx) {
  const unsigned H = (N_AGENTS * MSG) / 2; // 262144 (even split of iota)
  unsigned bits;
  if (idx < H) {                  // wave-uniform: idx range per wave is 64-aligned
    uint2 o = threefry_0_42(idx, idx + H);
    bits = o.x;
  } else {
    uint2 o = threefry_0_42(idx - H, idx);
    bits = o.y;
  }
  float f = __uint_as_float((bits >> 9) | 0x3f800000u) - 1.0f;
  float u = fmaxf(1e-10f, f + 1e-10f);   // (maxval-minval)==1.0f exactly in f32
  return -logf(-logf(u));
}

// ---------------- Kernel A: h = relu(zW+b), messages = hW+b, per-block colsum partials ----
__global__ __launch_bounds__(256) void k_encode(
    const float* __restrict__ z, const float* __restrict__ encW, const float* __restrict__ encB,
    const float* __restrict__ msgW, const float* __restrict__ msgB,
    float* __restrict__ h_out, float* __restrict__ m_out, float* __restrict__ partials)
{
  __shared__ float z_s[8][LATENT];
  __shared__ float encW_s[LATENT*HIDDEN];
  __shared__ float msgW_s[HIDDEN*MSG];
  __shared__ float h_s[8][HIDDEN];
  __shared__ float m_s[8][MSG];
  const int t  = threadIdx.x;
  const int r0 = blockIdx.x * 8;

  #pragma unroll
  for (int it = 0; it < 16; ++it) encW_s[t + 256*it] = encW[t + 256*it];
  #pragma unroll
  for (int it = 0; it < 8; ++it)  msgW_s[t + 256*it] = msgW[t + 256*it];
  #pragma unroll
  for (int it = 0; it < 4; ++it) {
    int q = t + 256*it;
    z_s[q >> 7][q & 127] = z[(size_t)r0*LATENT + q];
  }
  __syncthreads();

  { // h: 8 rows x 32 cols = 256 outputs
    int r = t >> 5, c = t & 31;
    float acc = encB[c];
    #pragma unroll
    for (int k = 0; k < LATENT; ++k) acc = fmaf(z_s[r][k], encW_s[k*HIDDEN + c], acc);
    float hv = fmaxf(acc, 0.0f);
    h_s[r][c] = hv;
    h_out[(size_t)(r0 + r)*HIDDEN + c] = hv;
  }
  __syncthreads();

  #pragma unroll
  for (int it = 0; it < 2; ++it) { // messages: 8 rows x 64 cols
    int r = (t >> 6) + 4*it, c = t & 63;
    float acc = msgB[c];
    #pragma unroll
    for (int k = 0; k < HIDDEN; ++k) acc = fmaf(h_s[r][k], msgW_s[k*MSG + c], acc);
    m_s[r][c] = acc;
    m_out[(size_t)(r0 + r)*MSG + c] = acc;
  }
  __syncthreads();

  if (t < MSG) { // per-block partial column sum of messages
    float p = 0.f;
    #pragma unroll
    for (int r = 0; r < 8; ++r) p += m_s[r][t];
    partials[(size_t)blockIdx.x*MSG + t] = p;
  }
}

// ---------------- Kernel A2: S[c] = sum over all 1024 block partials (f64) ------------
__global__ __launch_bounds__(1024) void k_colsum(
    const float* __restrict__ partials, double* __restrict__ S)
{
  __shared__ double red[16][MSG];
  const int t = threadIdx.x;
  const int c = t & 63, g = t >> 6;       // 16 groups
  double acc = 0.0;
  for (int p = 0; p < 64; ++p)
    acc += (double)partials[(size_t)(g*64 + p)*MSG + c];
  red[g][c] = acc;
  __syncthreads();
  #pragma unroll
  for (int s = 8; s > 0; s >>= 1) {
    if (g < s) red[g][c] += red[g + s][c];
    __syncthreads();
  }
  if (g == 0) S[c] = red[0][c];
}

// ---------------- Kernel BC: scan dist row -> E, agg = S - E, MLP epilogue + gumbel softmax
__global__ __launch_bounds__(256) void k_scan_out(
    const float* __restrict__ dists, const float* __restrict__ msg,
    const float* __restrict__ h_in, const double* __restrict__ S,
    const float* __restrict__ updW, const float* __restrict__ updB,
    const float* __restrict__ outW, const float* __restrict__ outB,
    const float* __restrict__ tau, float* __restrict__ out)
{
  __shared__ float x_s[4][CONCAT];
  __shared__ float h2_s[4][HIDDEN];
  const int w    = threadIdx.x >> 6;      // wave id: one wave per row
  const int lane = threadIdx.x & 63;      // lane owns message column `lane`
  const int i    = blockIdx.x * 4 + w;

  const f32x4* dp = (const f32x4*)(dists + (size_t)i * N_AGENTS);
  const float* mp = msg + lane;
  float e0 = 0.f, e1 = 0.f, e2 = 0.f, e3 = 0.f;

  // excluded entries: j==i or !(d < 1.5)  (complement of adj); aggregated = S - sum(excluded m)
  f32x4 cur = __builtin_nontemporal_load(dp + lane);  // nt: keep messages resident in L2
  for (int chunk = 0; chunk < N_AGENTS/256; ++chunk) {
    f32x4 nxt = cur;
    if (chunk + 1 < N_AGENTS/256)
      nxt = __builtin_nontemporal_load(dp + (chunk+1)*64 + lane);
    const int jb = chunk * 256;
    const int jl = jb + 4*lane;
    unsigned long long mk[4];
    mk[0] = __ballot(!(cur.x < THRESH) || (jl + 0 == i));
    mk[1] = __ballot(!(cur.y < THRESH) || (jl + 1 == i));
    mk[2] = __ballot(!(cur.z < THRESH) || (jl + 2 == i));
    mk[3] = __ballot(!(cur.w < THRESH) || (jl + 3 == i));
    #pragma unroll
    for (int k = 0; k < 4; ++k) {
      unsigned long long m = mk[k];                 // wave-uniform -> scalar control flow
      while (m) {
        int b0 = __builtin_ctzll(m); m &= m - 1;
        int b1 = -1, b2 = -1, b3 = -1;
        if (m) { b1 = __builtin_ctzll(m); m &= m - 1;
          if (m) { b2 = __builtin_ctzll(m); m &= m - 1;
            if (m) { b3 = __builtin_ctzll(m); m &= m - 1; } } }
        int j0 = jb + 4*b0 + k;
        int j1 = (b1 >= 0) ? (jb + 4*b1 + k) : j0;  // fallback -> same cache line (L1 hit)
        int j2 = (b2 >= 0) ? (jb + 4*b2 + k) : j0;
        int j3 = (b3 >= 0) ? (jb + 4*b3 + k) : j0;
        // 4 independent loads in flight (branch-free accumulate)
        float v0 = mp[(size_t)j0 * MSG];
        float v1 = mp[(size_t)j1 * MSG];
        float v2 = mp[(size_t)j2 * MSG];
        float v3 = mp[(size_t)j3 * MSG];
        e0 += v0;
        e1 += (b1 >= 0) ? v1 : 0.0f;
        e2 += (b2 >= 0) ? v2 : 0.0f;
        e3 += (b3 >= 0) ? v3 : 0.0f;
      }
    }
    cur = nxt;
  }
  double E = (double)((e0 + e1) + (e2 + e3));
  float agg = (float)(S[lane] - E);

  // stage concat vector x = [h_i (32), aggregated (64)]
  x_s[w][HIDDEN + lane] = agg;
  if (lane < HIDDEN) x_s[w][lane] = h_in[(size_t)i * HIDDEN + lane];
  __syncthreads();

  if (lane < HIDDEN) { // h2 = relu(x @ updW + b)
    float acc = updB[lane];
    #pragma unroll
    for (int k = 0; k < CONCAT; ++k) acc = fmaf(x_s[w][k], updW[k*HIDDEN + lane], acc);
    h2_s[w][lane] = fmaxf(acc, 0.0f);
  }
  __syncthreads();

  float lg = outB[lane]; // logits = h2 @ outW + b
  #pragma unroll
  for (int c = 0; c < HIDDEN; ++c) lg = fmaf(h2_s[w][c], outW[c*MSG + lane], lg);

  float tv = (lg + gumbel_at((unsigned)i*64u + (unsigned)lane)) / tau[0];

  float mx = tv;
  #pragma unroll
  for (int off = 32; off > 0; off >>= 1) mx = fmaxf(mx, __shfl_xor(mx, off, 64));
  float ex = expf(tv - mx);
  float sm = ex;
  #pragma unroll
  for (int off = 32; off > 0; off >>= 1) sm += __shfl_xor(sm, off, 64);
  out[(size_t)i * MSG + lane] = ex / sm;
}

extern "C" void kernel_launch(void* const* d_in, const int* in_sizes, int n_in,
                              void* d_out, int out_size, void* d_ws, size_t ws_size,
                              hipStream_t stream) {
  const float* z     = (const float*)d_in[0];
  const float* tau   = (const float*)d_in[1];
  const float* dists = (const float*)d_in[2];
  const float* encW  = (const float*)d_in[3];
  const float* encB  = (const float*)d_in[4];
  const float* msgW  = (const float*)d_in[5];
  const float* msgB  = (const float*)d_in[6];
  const float* updW  = (const float*)d_in[7];
  const float* updB  = (const float*)d_in[8];
  const float* outW  = (const float*)d_in[9];
  const float* outB  = (const float*)d_in[10];
  (void)in_sizes; (void)n_in; (void)out_size; (void)ws_size;

  char* ws = (char*)d_ws;
  float*  h_ws    = (float*)(ws);                         // 8192*32*4  = 1 MB
  float*  m_ws    = (float*)(ws + (1u<<20));              // 8192*64*4  = 2 MB
  float*  part_ws = (float*)(ws + (3u<<20));              // 1024*64*4  = 256 KB
  double* S_ws    = (double*)(ws + (3u<<20) + (1u<<18));  // 64*8       = 512 B
  float*  out     = (float*)d_out;

  hipLaunchKernelGGL(k_encode, dim3(N_AGENTS/8), dim3(256), 0, stream,
                     z, encW, encB, msgW, msgB, h_ws, m_ws, part_ws);
  hipLaunchKernelGGL(k_colsum, dim3(1), dim3(1024), 0, stream, part_ws, S_ws);
  hipLaunchKernelGGL(k_scan_out, dim3(N_AGENTS/4), dim3(256), 0, stream,
                     dists, m_ws, h_ws, S_ws, updW, updB, outW, outB, tau, out);
}

// Round 2
// 428.407 us; speedup vs baseline: 1.2860x; 1.2860x over previous
//
#include <hip/hip_runtime.h>
#include <hip/hip_bf16.h>
#include <math.h>

#define N_AGENTS 8192
#define LATENT   128
#define HIDDEN   32
#define MSG      64
#define CONCAT   96      // HIDDEN + MSG
#define THRESH   1.5f
#define KSPLIT   16      // K-split factor for the MFMA aggregation

typedef float f32x4  __attribute__((ext_vector_type(4)));
typedef short bf16x8 __attribute__((ext_vector_type(8)));  // 8 bf16 in 4 VGPRs

// ---------------- JAX threefry2x32, key = (0, 42) ----------------
__device__ __forceinline__ unsigned rotl32(unsigned x, unsigned r) {
  return (x << r) | (x >> (32u - r));
}
__device__ __forceinline__ void tf_round(unsigned &x0, unsigned &x1, unsigned r) {
  x0 += x1; x1 = rotl32(x1, r); x1 ^= x0;
}
__device__ __forceinline__ uint2 threefry_0_42(unsigned x0, unsigned x1) {
  const unsigned k0 = 0u, k1 = 42u, k2 = 0x1BD11BDAu ^ 0u ^ 42u;
  x0 += k0; x1 += k1;
  tf_round(x0,x1,13); tf_round(x0,x1,15); tf_round(x0,x1,26); tf_round(x0,x1, 6);
  x0 += k1; x1 += k2 + 1u;
  tf_round(x0,x1,17); tf_round(x0,x1,29); tf_round(x0,x1,16); tf_round(x0,x1,24);
  x0 += k2; x1 += k0 + 2u;
  tf_round(x0,x1,13); tf_round(x0,x1,15); tf_round(x0,x1,26); tf_round(x0,x1, 6);
  x0 += k0; x1 += k1 + 3u;
  tf_round(x0,x1,17); tf_round(x0,x1,29); tf_round(x0,x1,16); tf_round(x0,x1,24);
  x0 += k1; x1 += k2 + 4u;
  tf_round(x0,x1,13); tf_round(x0,x1,15); tf_round(x0,x1,26); tf_round(x0,x1, 6);
  x0 += k2; x1 += k0 + 5u;
  return make_uint2(x0, x1);
}

__device__ __forceinline__ float gumbel_at(unsigned idx) {
  const unsigned H = (N_AGENTS * MSG) / 2; // 262144
  unsigned bits;
  if (idx < H) {                  // wave-uniform (idx ranges are 64-aligned)
    uint2 o = threefry_0_42(idx, idx + H);
    bits = o.x;
  } else {
    uint2 o = threefry_0_42(idx - H, idx);
    bits = o.y;
  }
  float f = __uint_as_float((bits >> 9) | 0x3f800000u) - 1.0f;
  float u = fmaxf(1e-10f, f + 1e-10f);
  return -logf(-logf(u));
}

__device__ __forceinline__ unsigned short f2bf(float x) { // RNE f32 -> bf16
  unsigned u = __float_as_uint(x);
  u += 0x7FFFu + ((u >> 16) & 1u);
  return (unsigned short)(u >> 16);
}

// ---------------- Kernel A: h = relu(zW+b); messages bf16 row-major + transposed ----
__global__ __launch_bounds__(256) void k_encode(
    const float* __restrict__ z, const float* __restrict__ encW, const float* __restrict__ encB,
    const float* __restrict__ msgW, const float* __restrict__ msgB,
    float* __restrict__ h_out, unsigned* __restrict__ msgR_u32,
    unsigned short* __restrict__ msgT)
{
  __shared__ float z_s[8][LATENT];
  __shared__ float encW_s[LATENT*HIDDEN];
  __shared__ float msgW_s[HIDDEN*MSG];
  __shared__ float h_s[8][HIDDEN];
  __shared__ float m_s[8][MSG];
  const int t  = threadIdx.x;
  const int r0 = blockIdx.x * 8;

  #pragma unroll
  for (int it = 0; it < 16; ++it) encW_s[t + 256*it] = encW[t + 256*it];
  #pragma unroll
  for (int it = 0; it < 8; ++it)  msgW_s[t + 256*it] = msgW[t + 256*it];
  #pragma unroll
  for (int it = 0; it < 4; ++it) {
    int q = t + 256*it;
    z_s[q >> 7][q & 127] = z[(size_t)r0*LATENT + q];
  }
  __syncthreads();

  { // h: 8 rows x 32 cols
    int r = t >> 5, c = t & 31;
    float acc = encB[c];
    #pragma unroll
    for (int k = 0; k < LATENT; ++k) acc = fmaf(z_s[r][k], encW_s[k*HIDDEN + c], acc);
    float hv = fmaxf(acc, 0.0f);
    h_s[r][c] = hv;
    h_out[(size_t)(r0 + r)*HIDDEN + c] = hv;
  }
  __syncthreads();

  #pragma unroll
  for (int it = 0; it < 2; ++it) { // messages: 8 rows x 64 cols
    int r = (t >> 6) + 4*it, c = t & 63;
    float acc = msgB[c];
    #pragma unroll
    for (int k = 0; k < HIDDEN; ++k) acc = fmaf(h_s[r][k], msgW_s[k*MSG + c], acc);
    m_s[r][c] = acc;
  }
  __syncthreads();

  { // msgR (row-major bf16, packed u32): flat u32 index = r*32 + c0/2
    int r = t >> 5, c0 = (t & 31) * 2;
    unsigned lo = f2bf(m_s[r][c0]), hi = f2bf(m_s[r][c0 + 1]);
    msgR_u32[(size_t)(r0 + r)*32 + (t & 31)] = lo | (hi << 16);
  }
  { // msgT (transposed bf16 [64][8192]): thread t writes rows (t>>6)*2, +1 of col c
    int c = t & 63, rr = (t >> 6) * 2;
    unsigned lo = f2bf(m_s[rr][c]), hi = f2bf(m_s[rr + 1][c]);
    *(unsigned*)(msgT + (size_t)c*N_AGENTS + r0 + rr) = lo | (hi << 16);
  }
}

// ---------------- Kernel B: C += adj @ msg via bf16 MFMA, K-split + f32 atomics ----
// wave: 32 rows x 64 cols, K-chunk of 512. A built in-regs from dists (0/1 bf16).
// mfma_f32_16x16x32_bf16 layouts (verified): A[m=lane&15][k=(lane>>4)*8+j],
// B[k=(lane>>4)*8+j][n=lane&15], C/D: col=lane&15, row=(lane>>4)*4+reg.
__device__ __forceinline__ bf16x8 adj_frag(f32x4 lo, f32x4 hi) {
  union { bf16x8 v; unsigned u[4]; } r;
  r.u[0] = (lo.x < THRESH ? 0x3F80u : 0u) | (lo.y < THRESH ? 0x3F800000u : 0u);
  r.u[1] = (lo.z < THRESH ? 0x3F80u : 0u) | (lo.w < THRESH ? 0x3F800000u : 0u);
  r.u[2] = (hi.x < THRESH ? 0x3F80u : 0u) | (hi.y < THRESH ? 0x3F800000u : 0u);
  r.u[3] = (hi.z < THRESH ? 0x3F80u : 0u) | (hi.w < THRESH ? 0x3F800000u : 0u);
  return r.v;
}

__global__ __launch_bounds__(256, 4) void k_agg(
    const float* __restrict__ dists, const unsigned short* __restrict__ msgT,
    float* __restrict__ C)
{
  const int lane = threadIdx.x & 63;
  const int wv   = threadIdx.x >> 6;
  const int W    = blockIdx.x * 4 + wv;        // 4096 waves
  const int rowTile = W & 255;                 // 256 row tiles of 32
  const int kslice  = W >> 8;                  // 0..15
  const int row0 = rowTile * 32;
  const int k0   = kslice * (N_AGENTS / KSPLIT);   // 512-wide K chunk
  const int m = lane & 15, q = lane >> 4;

  const float* a0p = dists + (size_t)(row0 + m) * N_AGENTS + k0 + q*8;
  const float* a1p = a0p + (size_t)16 * N_AGENTS;
  const unsigned short* b0p = msgT + (size_t)(m)      * N_AGENTS + k0 + q*8;
  const unsigned short* b1p = msgT + (size_t)(m + 16) * N_AGENTS + k0 + q*8;
  const unsigned short* b2p = msgT + (size_t)(m + 32) * N_AGENTS + k0 + q*8;
  const unsigned short* b3p = msgT + (size_t)(m + 48) * N_AGENTS + k0 + q*8;

  f32x4 acc[2][4];
  #pragma unroll
  for (int g = 0; g < 2; ++g)
    #pragma unroll
    for (int nt = 0; nt < 4; ++nt) acc[g][nt] = (f32x4)0.0f;

  #pragma unroll
  for (int kk = 0; kk < (N_AGENTS / KSPLIT) / 32; ++kk) {  // 16 iterations, K-step 32
    const int off = kk * 32;
    f32x4 a00 = __builtin_nontemporal_load((const f32x4*)(a0p + off));
    f32x4 a01 = __builtin_nontemporal_load((const f32x4*)(a0p + off + 4));
    f32x4 a10 = __builtin_nontemporal_load((const f32x4*)(a1p + off));
    f32x4 a11 = __builtin_nontemporal_load((const f32x4*)(a1p + off + 4));
    bf16x8 b0 = *(const bf16x8*)(b0p + off);
    bf16x8 b1 = *(const bf16x8*)(b1p + off);
    bf16x8 b2 = *(const bf16x8*)(b2p + off);
    bf16x8 b3 = *(const bf16x8*)(b3p + off);
    bf16x8 af0 = adj_frag(a00, a01);
    bf16x8 af1 = adj_frag(a10, a11);
    acc[0][0] = __builtin_amdgcn_mfma_f32_16x16x32_bf16(af0, b0, acc[0][0], 0, 0, 0);
    acc[0][1] = __builtin_amdgcn_mfma_f32_16x16x32_bf16(af0, b1, acc[0][1], 0, 0, 0);
    acc[0][2] = __builtin_amdgcn_mfma_f32_16x16x32_bf16(af0, b2, acc[0][2], 0, 0, 0);
    acc[0][3] = __builtin_amdgcn_mfma_f32_16x16x32_bf16(af0, b3, acc[0][3], 0, 0, 0);
    acc[1][0] = __builtin_amdgcn_mfma_f32_16x16x32_bf16(af1, b0, acc[1][0], 0, 0, 0);
    acc[1][1] = __builtin_amdgcn_mfma_f32_16x16x32_bf16(af1, b1, acc[1][1], 0, 0, 0);
    acc[1][2] = __builtin_amdgcn_mfma_f32_16x16x32_bf16(af1, b2, acc[1][2], 0, 0, 0);
    acc[1][3] = __builtin_amdgcn_mfma_f32_16x16x32_bf16(af1, b3, acc[1][3], 0, 0, 0);
  }

  #pragma unroll
  for (int g = 0; g < 2; ++g)
    #pragma unroll
    for (int nt = 0; nt < 4; ++nt)
      #pragma unroll
      for (int r = 0; r < 4; ++r)
        atomicAdd(&C[(size_t)(row0 + g*16 + q*4 + r) * MSG + nt*16 + m], acc[g][nt][r]);
}

// ---------------- Kernel C: epilogue — diag fix, upd/out MLP, gumbel softmax ----
__global__ __launch_bounds__(256) void k_out(
    const float* __restrict__ C, const float* __restrict__ dists,
    const unsigned short* __restrict__ msgR,
    const float* __restrict__ h_in,
    const float* __restrict__ updW, const float* __restrict__ updB,
    const float* __restrict__ outW, const float* __restrict__ outB,
    const float* __restrict__ tau, float* __restrict__ out)
{
  __shared__ float x_s[4][CONCAT];
  __shared__ float h2_s[4][HIDDEN];
  const int w    = threadIdx.x >> 6;
  const int lane = threadIdx.x & 63;
  const int i    = blockIdx.x * 4 + w;

  float agg = C[(size_t)i * MSG + lane];
  float dii = dists[(size_t)i * (N_AGENTS + 1)];
  if (dii < THRESH) { // remove diagonal contribution (adj has zero diagonal)
    unsigned short us = msgR[(size_t)i * MSG + lane];
    agg -= __uint_as_float(((unsigned)us) << 16);
  }

  x_s[w][HIDDEN + lane] = agg;
  if (lane < HIDDEN) x_s[w][lane] = h_in[(size_t)i * HIDDEN + lane];
  __syncthreads();

  if (lane < HIDDEN) {
    float acc = updB[lane];
    #pragma unroll
    for (int k = 0; k < CONCAT; ++k) acc = fmaf(x_s[w][k], updW[k*HIDDEN + lane], acc);
    h2_s[w][lane] = fmaxf(acc, 0.0f);
  }
  __syncthreads();

  float lg = outB[lane];
  #pragma unroll
  for (int c = 0; c < HIDDEN; ++c) lg = fmaf(h2_s[w][c], outW[c*MSG + lane], lg);

  float tv = (lg + gumbel_at((unsigned)i*64u + (unsigned)lane)) / tau[0];

  float mx = tv;
  #pragma unroll
  for (int off = 32; off > 0; off >>= 1) mx = fmaxf(mx, __shfl_xor(mx, off, 64));
  float ex = expf(tv - mx);
  float sm = ex;
  #pragma unroll
  for (int off = 32; off > 0; off >>= 1) sm += __shfl_xor(sm, off, 64);
  out[(size_t)i * MSG + lane] = ex / sm;
}

extern "C" void kernel_launch(void* const* d_in, const int* in_sizes, int n_in,
                              void* d_out, int out_size, void* d_ws, size_t ws_size,
                              hipStream_t stream) {
  const float* z     = (const float*)d_in[0];
  const float* tau   = (const float*)d_in[1];
  const float* dists = (const float*)d_in[2];
  const float* encW  = (const float*)d_in[3];
  const float* encB  = (const float*)d_in[4];
  const float* msgW  = (const float*)d_in[5];
  const float* msgB  = (const float*)d_in[6];
  const float* updW  = (const float*)d_in[7];
  const float* updB  = (const float*)d_in[8];
  const float* outW  = (const float*)d_in[9];
  const float* outB  = (const float*)d_in[10];
  (void)in_sizes; (void)n_in; (void)out_size; (void)ws_size;

  char* ws = (char*)d_ws;
  float*          C_ws  = (float*)(ws);                    // 8192*64*4 = 2 MB
  float*          h_ws  = (float*)(ws + (2u<<20));         // 8192*32*4 = 1 MB
  unsigned short* msgR  = (unsigned short*)(ws + (3u<<20)); // 8192*64*2 = 1 MB
  unsigned short* msgT  = (unsigned short*)(ws + (4u<<20)); // 64*8192*2 = 1 MB
  float* out = (float*)d_out;

  hipMemsetAsync(C_ws, 0, (size_t)N_AGENTS * MSG * sizeof(float), stream);
  hipLaunchKernelGGL(k_encode, dim3(N_AGENTS/8), dim3(256), 0, stream,
                     z, encW, encB, msgW, msgB, h_ws, (unsigned*)msgR, msgT);
  hipLaunchKernelGGL(k_agg, dim3((256 * KSPLIT) / 4), dim3(256), 0, stream,
                     dists, msgT, C_ws);
  hipLaunchKernelGGL(k_out, dim3(N_AGENTS/4), dim3(256), 0, stream,
                     C_ws, dists, msgR, h_ws, updW, updB, outW, outB, tau, out);
}